// Round 12
// baseline (723.277 us; speedup 1.0000x reference)
//
#include <hip/hip_runtime.h>
#include <hip/hip_bf16.h>

typedef __bf16 bf16_t;
typedef __bf16 bf16x8 __attribute__((ext_vector_type(8)));
typedef float  f32x4  __attribute__((ext_vector_type(4)));

#define DK 1024   // d_in  (K)
#define DN 1024   // d_out (N)
#define RNK 32
#define BM 128
#define BN 512
#define BK 32
#define NKT 32

// ---- Pass 1: W_eff = W + C @ V_r^T, bf16, PRE-SWIZZLED (R7 layout) ---------
__global__ void weff_kernel(const float* __restrict__ W,
                            const float* __restrict__ Vr,
                            const float* __restrict__ C,
                            bf16_t* __restrict__ WeffSw)
{
    const int o  = blockIdx.x;
    const int g  = threadIdx.x;
    const int d0 = g * 8;

    f32x4 cv[8];
#pragma unroll
    for (int q = 0; q < 8; ++q) cv[q] = *(const f32x4*)(C + o * RNK + q * 4);

    const f32x4* wrow = (const f32x4*)(W + (size_t)o * DK + d0);
    f32x4 w0 = wrow[0], w1 = wrow[1];
    float acc[8];
#pragma unroll
    for (int e = 0; e < 4; ++e) { acc[e] = w0[e]; acc[4 + e] = w1[e]; }

#pragma unroll
    for (int e = 0; e < 8; ++e) {
        const f32x4* vre = (const f32x4*)(Vr + (size_t)(d0 + e) * RNK);
        float s = 0.f;
#pragma unroll
        for (int q = 0; q < 8; ++q) {
            f32x4 v = vre[q];
            s += cv[q][0] * v[0] + cv[q][1] * v[1] + cv[q][2] * v[2] + cv[q][3] * v[3];
        }
        acc[e] += s;
    }

    bf16x8 out;
#pragma unroll
    for (int e = 0; e < 8; ++e) out[e] = (bf16_t)acc[e];

    const int bn = o >> 9, rloc = o & 511;
    const int kt = d0 >> 5, seg = (d0 >> 3) & 3;
    const int sw = seg ^ ((rloc >> 1) & 3);
    const size_t byte = (size_t)(bn * 32 + kt) * 32768 + rloc * 64 + (sw << 4);
    *(bf16x8*)((char*)WeffSw + byte) = out;
}

// ---- Pass 2: R7 GEMM verbatim (best known, 200 us anchor) ------------------
__global__ __launch_bounds__(512, 1) void corrlin_gemm_kernel(
    const float* __restrict__ X, const bf16_t* __restrict__ WeffSw,
    const float* __restrict__ bias, float* __restrict__ Out)
{
    __shared__ __align__(16) char smem[81920];
    char* Ab0 = smem;
    char* Ab1 = smem + 8192;
    char* Bb0 = smem + 16384;
    char* Bb1 = smem + 49152;

    const int tid = threadIdx.x;
    const int b0  = blockIdx.x;
    const int L  = (b0 & 7) * 128 + (b0 >> 3);
    const int bm = L >> 1;
    const int bn = L & 1;
    const int m0 = bm * BM;

    const int lane = tid & 63;
    const int wn   = tid >> 6;
    const int arow = tid >> 2;
    const int aseg = tid & 3;

    f32x4 acc[8][4] = {};
    f32x4 set0[2], set1[2];

    auto issueA = [&](int kt, f32x4* s) {
        const float* p = X + (size_t)(m0 + arow) * DK + kt * BK + aseg * 8;
        s[0] = *(const f32x4*)p;
        s[1] = *(const f32x4*)(p + 4);
    };
    auto storeA = [&](const f32x4* s, char* Ab) {
        const int sw = aseg ^ ((arow >> 1) & 3);
        bf16x8 v;
#pragma unroll
        for (int j = 0; j < 4; ++j) { v[j] = (bf16_t)s[0][j]; v[4 + j] = (bf16_t)s[1][j]; }
        *(bf16x8*)(Ab + arow * 64 + (sw << 4)) = v;
    };
    auto issueB = [&](int kt, char* Bb) {
        const char* g = (const char*)WeffSw + (size_t)(bn * 32 + kt) * 32768;
#pragma unroll
        for (int c = 0; c < 4; ++c) {
            const int lin = c * 8192 + wn * 1024;
            __builtin_amdgcn_global_load_lds(
                (const __attribute__((address_space(1))) void*)(g + lin + lane * 16),
                (__attribute__((address_space(3))) void*)(Bb + lin),
                16, 0, 0);
        }
    };
    auto readB = [&](const char* Bc, bf16x8* bfr) {
        const int kb = lane >> 4;
#pragma unroll
        for (int nf = 0; nf < 4; ++nf) {
            const int row = wn * 64 + nf * 16 + (lane & 15);
            bfr[nf] = *(const bf16x8*)(Bc + row * 64 + ((kb ^ ((row >> 1) & 3)) << 4));
        }
    };
    auto compute_h = [&](const char* Ac, int h, const bf16x8* bfr) {
        bf16x8 af[4];
        const int kb = lane >> 4;
#pragma unroll
        for (int i = 0; i < 4; ++i) {
            const int row = (h * 4 + i) * 16 + (lane & 15);
            af[i] = *(const bf16x8*)(Ac + row * 64 + ((kb ^ ((row >> 1) & 3)) << 4));
        }
        __builtin_amdgcn_s_setprio(1);
#pragma unroll
        for (int i = 0; i < 4; ++i)
#pragma unroll
            for (int nf = 0; nf < 4; ++nf)
                acc[h * 4 + i][nf] = __builtin_amdgcn_mfma_f32_16x16x32_bf16(
                    af[i], bfr[nf], acc[h * 4 + i][nf], 0, 0, 0);
        __builtin_amdgcn_s_setprio(0);
    };

    auto iter = [&](int t, const char* Ac, const char* Bc, char* An, char* Bn,
                    f32x4* aStore, f32x4* aFill) {
        if (t + 1 < NKT) issueB(t + 1, Bn);
        bf16x8 bfr[4];
        readB(Bc, bfr);
        compute_h(Ac, 0, bfr);
        if (t + 1 < NKT) storeA(aStore, An);
        if (t + 2 < NKT) issueA(t + 2, aFill);
        compute_h(Ac, 1, bfr);
        if (t + 2 < NKT) {
            asm volatile("s_waitcnt vmcnt(2) lgkmcnt(0)" ::: "memory");
            __builtin_amdgcn_s_barrier();
        } else if (t + 1 < NKT) {
            asm volatile("s_waitcnt vmcnt(0) lgkmcnt(0)" ::: "memory");
            __builtin_amdgcn_s_barrier();
        }
    };

    issueA(0, set0);
    issueB(0, Bb0);
    storeA(set0, Ab0);
    issueA(1, set1);
    asm volatile("s_waitcnt vmcnt(2) lgkmcnt(0)" ::: "memory");
    __builtin_amdgcn_s_barrier();

    for (int t = 0; t < NKT; t += 2) {
        iter(t,     Ab0, Bb0, Ab1, Bb1, set1, set0);
        iter(t + 1, Ab1, Bb1, Ab0, Bb0, set0, set1);
    }
    __syncthreads();

    float* tb = (float*)smem + wn * 1280;
    const int nbase = bn * BN + wn * 64;
    float bv[4];
#pragma unroll
    for (int nf = 0; nf < 4; ++nf) bv[nf] = bias[nbase + nf * 16 + (lane & 15)];

#pragma unroll
    for (int mf = 0; mf < 8; ++mf) {
#pragma unroll
        for (int nf = 0; nf < 4; ++nf)
#pragma unroll
            for (int j = 0; j < 4; ++j) {
                const int r = (lane >> 4) * 4 + j;
                const int c = nf * 16 + (lane & 15);
                tb[r * 80 + c] = acc[mf][nf][j] + bv[nf];
            }
        __syncthreads();
#pragma unroll
        for (int jj = 0; jj < 4; ++jj) {
            const int rr = jj * 4 + (lane >> 4);
            const int cc = (lane & 15) * 4;
            f32x4 v = *(const f32x4*)&tb[rr * 80 + cc];
            *(f32x4*)&Out[(size_t)(m0 + mf * 16 + rr) * DN + nbase + cc] = v;
        }
        __syncthreads();
    }
}

// ======================= ABLATION PROBES (write d_ws only) ==================
// Probe 1 (REP=2, timing via total-subtraction): pure MFMA + barrier pattern.
__global__ __launch_bounds__(512, 1) void probe_mfmaonly(float* ws)
{
    __shared__ __align__(16) char smem[1024];
    const int tid = threadIdx.x;
    const int lane = tid & 63;
    if (tid < 64) *(f32x4*)(smem + tid * 16) = f32x4{0.f, 0.f, 0.f, 0.f};
    __syncthreads();
    bf16x8 af[4], bfr[4];
#pragma unroll
    for (int i = 0; i < 4; ++i) {
        af[i]  = *(const bf16x8*)(smem + ((lane * 16 + i * 16) & 1023));
        bfr[i] = *(const bf16x8*)(smem + ((lane * 16 + i * 16 + 512) & 1023));
    }
    f32x4 acc[8][4] = {};
    for (int rep = 0; rep < 2; ++rep)
    for (int t = 0; t < NKT; ++t) {
#pragma unroll
        for (int h = 0; h < 2; ++h) {
            __builtin_amdgcn_s_setprio(1);
#pragma unroll
            for (int i = 0; i < 4; ++i)
#pragma unroll
                for (int nf = 0; nf < 4; ++nf)
                    acc[h * 4 + i][nf] = __builtin_amdgcn_mfma_f32_16x16x32_bf16(
                        af[i], bfr[nf], acc[h * 4 + i][nf], 0, 0, 0);
            __builtin_amdgcn_s_setprio(0);
        }
        asm volatile("s_waitcnt lgkmcnt(0)" ::: "memory");
        __builtin_amdgcn_s_barrier();
    }
    float s = 0.f;
#pragma unroll
    for (int mf = 0; mf < 8; ++mf)
#pragma unroll
        for (int nf = 0; nf < 4; ++nf)
#pragma unroll
            for (int j = 0; j < 4; ++j) s += acc[mf][nf][j];
    asm volatile("" :: "v"(s));
    if (tid == 0) ws[blockIdx.x] = s;
}

// Probe 2 (REP=6, visible in top-5): R7 swizzled LDS frag reads + MFMA +
// barriers, no staging. t_lds = dur/6. Per-iter memory clobber blocks
// hoisting of the ds_reads (rule-17 hygiene).
__global__ __launch_bounds__(512, 1) void probe_ldsmfma(float* ws)
{
    __shared__ __align__(16) char smem[81920];
    char* Ab0 = smem;
    char* Ab1 = smem + 8192;
    char* Bb0 = smem + 16384;
    char* Bb1 = smem + 49152;

    const int tid = threadIdx.x;
    const int lane = tid & 63;
    const int wn   = tid >> 6;
    for (int i = tid; i < 81920 / 16; i += 512)
        *(f32x4*)(smem + i * 16) = f32x4{0.f, 0.f, 0.f, 0.f};
    __syncthreads();

    f32x4 acc[8][4] = {};
    auto readB = [&](const char* Bc, bf16x8* bfr) {
        const int kb = lane >> 4;
#pragma unroll
        for (int nf = 0; nf < 4; ++nf) {
            const int row = wn * 64 + nf * 16 + (lane & 15);
            bfr[nf] = *(const bf16x8*)(Bc + row * 64 + ((kb ^ ((row >> 1) & 3)) << 4));
        }
    };
    auto compute_h = [&](const char* Ac, int h, const bf16x8* bfr) {
        bf16x8 af[4];
        const int kb = lane >> 4;
#pragma unroll
        for (int i = 0; i < 4; ++i) {
            const int row = (h * 4 + i) * 16 + (lane & 15);
            af[i] = *(const bf16x8*)(Ac + row * 64 + ((kb ^ ((row >> 1) & 3)) << 4));
        }
        __builtin_amdgcn_s_setprio(1);
#pragma unroll
        for (int i = 0; i < 4; ++i)
#pragma unroll
            for (int nf = 0; nf < 4; ++nf)
                acc[h * 4 + i][nf] = __builtin_amdgcn_mfma_f32_16x16x32_bf16(
                    af[i], bfr[nf], acc[h * 4 + i][nf], 0, 0, 0);
        __builtin_amdgcn_s_setprio(0);
    };

    for (int rep = 0; rep < 6; ++rep)
    for (int t = 0; t < NKT; ++t) {
        const char* Ac = (t & 1) ? Ab1 : Ab0;
        const char* Bc = (t & 1) ? Bb1 : Bb0;
        bf16x8 bfr[4];
        readB(Bc, bfr);
        compute_h(Ac, 0, bfr);
        compute_h(Ac, 1, bfr);
        asm volatile("s_waitcnt lgkmcnt(0)" ::: "memory");
        __builtin_amdgcn_s_barrier();
    }
    float s = 0.f;
#pragma unroll
    for (int mf = 0; mf < 8; ++mf)
#pragma unroll
        for (int nf = 0; nf < 4; ++nf)
#pragma unroll
            for (int j = 0; j < 4; ++j) s += acc[mf][nf][j];
    asm volatile("" :: "v"(s));
    if (tid == 0) ws[blockIdx.x] = s;
}

extern "C" void kernel_launch(void* const* d_in, const int* in_sizes, int n_in,
                              void* d_out, int out_size, void* d_ws, size_t ws_size,
                              hipStream_t stream) {
    const float* x  = (const float*)d_in[0];
    const float* W  = (const float*)d_in[1];
    const float* b  = (const float*)d_in[2];
    const float* Vr = (const float*)d_in[3];
    const float* C  = (const float*)d_in[4];
    float* out = (float*)d_out;

    const int M = in_sizes[0] / DK;            // 65536
    bf16_t* WeffSw = (bf16_t*)d_ws;            // 2 MB pre-swizzled W_eff
    float* wsp = (float*)((char*)d_ws + (2u << 20));   // probe sinks

    weff_kernel<<<DN, 128, 0, stream>>>(W, Vr, C, WeffSw);

    const int mtiles = M / BM;                 // 512
    const int nwg = mtiles * (DN / BN);        // 1024
    corrlin_gemm_kernel<<<nwg, 512, 0, stream>>>(x, WeffSw, b, out);

    // ---- ablation probes (outputs to d_ws; timing via rocprof/subtraction) -
    probe_mfmaonly<<<nwg, 512, 0, stream>>>(wsp);            // REP=2
    probe_ldsmfma <<<nwg, 512, 0, stream>>>(wsp + 1024);     // REP=6
}

// Round 13
// 202.662 us; speedup vs baseline: 3.5689x; 3.5689x over previous
//
#include <hip/hip_runtime.h>
#include <hip/hip_bf16.h>

typedef __bf16 bf16_t;
typedef __bf16 bf16x8 __attribute__((ext_vector_type(8)));
typedef float  f32x4  __attribute__((ext_vector_type(4)));

#define DK 1024   // d_in  (K)
#define DN 1024   // d_out (N)
#define RNK 32
#define BM 128
#define BN 512
#define BK 32
#define NKT 32

// ---- Pass 1: W_eff = W + C @ V_r^T, bf16, PRE-SWIZZLED (R7 layout) ---------
__global__ void weff_kernel(const float* __restrict__ W,
                            const float* __restrict__ Vr,
                            const float* __restrict__ C,
                            bf16_t* __restrict__ WeffSw)
{
    const int o  = blockIdx.x;
    const int g  = threadIdx.x;
    const int d0 = g * 8;

    f32x4 cv[8];
#pragma unroll
    for (int q = 0; q < 8; ++q) cv[q] = *(const f32x4*)(C + o * RNK + q * 4);

    const f32x4* wrow = (const f32x4*)(W + (size_t)o * DK + d0);
    f32x4 w0 = wrow[0], w1 = wrow[1];
    float acc[8];
#pragma unroll
    for (int e = 0; e < 4; ++e) { acc[e] = w0[e]; acc[4 + e] = w1[e]; }

#pragma unroll
    for (int e = 0; e < 8; ++e) {
        const f32x4* vre = (const f32x4*)(Vr + (size_t)(d0 + e) * RNK);
        float s = 0.f;
#pragma unroll
        for (int q = 0; q < 8; ++q) {
            f32x4 v = vre[q];
            s += cv[q][0] * v[0] + cv[q][1] * v[1] + cv[q][2] * v[2] + cv[q][3] * v[3];
        }
        acc[e] += s;
    }

    bf16x8 out;
#pragma unroll
    for (int e = 0; e < 8; ++e) out[e] = (bf16_t)acc[e];

    const int bn = o >> 9, rloc = o & 511;
    const int kt = d0 >> 5, seg = (d0 >> 3) & 3;
    const int sw = seg ^ ((rloc >> 1) & 3);
    const size_t byte = (size_t)(bn * 32 + kt) * 32768 + rloc * 64 + (sw << 4);
    *(bf16x8*)((char*)WeffSw + byte) = out;
}

// ---- Pass 2: R7 compute core + depth-3/4 prefetch pipeline -----------------
// B: 4 LDS bufs, issueB(t+3) -> 3-iter lead. A: 4 reg sets, issueA(t+4) ->
// 4-iter lead. Constant counted vmcnt(14) at iter end drains exactly B(t+1),
// keeping 14 loads in flight (derived by per-wave queue-order counting).
__global__ __launch_bounds__(512, 1) void corrlin_gemm_kernel(
    const float* __restrict__ X, const bf16_t* __restrict__ WeffSw,
    const float* __restrict__ bias, float* __restrict__ Out)
{
    __shared__ __align__(16) char smem[147456];
    char* Ab0 = smem;                 // 8KB each (128 x 32 bf16)
    char* Ab1 = smem + 8192;
    char* Bq0 = smem + 16384;         // 32KB each (512 x 32 bf16)
    char* Bq1 = smem + 49152;
    char* Bq2 = smem + 81920;
    char* Bq3 = smem + 114688;

    const int tid = threadIdx.x;
    const int b0  = blockIdx.x;
    const int L  = (b0 & 7) * 128 + (b0 >> 3);   // XCD-bijective, nwg=1024
    const int bm = L >> 1;
    const int bn = L & 1;
    const int m0 = bm * BM;

    const int lane = tid & 63;
    const int wn   = tid >> 6;
    const int arow = tid >> 2;
    const int aseg = tid & 3;

    f32x4 acc[8][4] = {};
    f32x4 s0[2], s1[2], s2[2], s3[2];   // 4 named A-reg sets (depth-4)

    auto issueA = [&](int kt, f32x4* s) {
        const float* p = X + (size_t)(m0 + arow) * DK + kt * BK + aseg * 8;
        s[0] = *(const f32x4*)p;
        s[1] = *(const f32x4*)(p + 4);
    };
    auto storeA = [&](const f32x4* s, char* Ab) {
        const int sw = aseg ^ ((arow >> 1) & 3);
        bf16x8 v;
#pragma unroll
        for (int j = 0; j < 4; ++j) { v[j] = (bf16_t)s[0][j]; v[4 + j] = (bf16_t)s[1][j]; }
        *(bf16x8*)(Ab + arow * 64 + (sw << 4)) = v;
    };
    auto issueB = [&](int kt, char* Bb) {
        const char* g = (const char*)WeffSw + (size_t)(bn * 32 + kt) * 32768;
#pragma unroll
        for (int c = 0; c < 4; ++c) {
            const int lin = c * 8192 + wn * 1024;
            __builtin_amdgcn_global_load_lds(
                (const __attribute__((address_space(1))) void*)(g + lin + lane * 16),
                (__attribute__((address_space(3))) void*)(Bb + lin),
                16, 0, 0);
        }
    };
    auto readB = [&](const char* Bc, bf16x8* bfr) {
        const int kb = lane >> 4;
#pragma unroll
        for (int nf = 0; nf < 4; ++nf) {
            const int row = wn * 64 + nf * 16 + (lane & 15);
            bfr[nf] = *(const bf16x8*)(Bc + row * 64 + ((kb ^ ((row >> 1) & 3)) << 4));
        }
    };
    auto compute_h = [&](const char* Ac, int h, const bf16x8* bfr) {
        bf16x8 af[4];
        const int kb = lane >> 4;
#pragma unroll
        for (int i = 0; i < 4; ++i) {
            const int row = (h * 4 + i) * 16 + (lane & 15);
            af[i] = *(const bf16x8*)(Ac + row * 64 + ((kb ^ ((row >> 1) & 3)) << 4));
        }
        __builtin_amdgcn_s_setprio(1);
#pragma unroll
        for (int i = 0; i < 4; ++i)
#pragma unroll
            for (int nf = 0; nf < 4; ++nf)
                acc[h * 4 + i][nf] = __builtin_amdgcn_mfma_f32_16x16x32_bf16(
                    af[i], bfr[nf], acc[h * 4 + i][nf], 0, 0, 0);
        __builtin_amdgcn_s_setprio(0);
    };

    // steady-state iteration (guard-free, t+4 <= 31)
    auto iter_main = [&](int t, const char* Ac, char* An, const char* Bc, char* Bn3,
                         const f32x4* sStore /*A(t+1)*/, f32x4* sFill /*A(t+4)*/) {
        issueB(t + 3, Bn3);
        bf16x8 bfr[4];
        readB(Bc, bfr);
        compute_h(Ac, 0, bfr);
        storeA(sStore, An);          // auto-waits its 2 loads (3-iter lead)
        issueA(t + 4, sFill);
        compute_h(Ac, 1, bfr);
        asm volatile("s_waitcnt vmcnt(14) lgkmcnt(0)" ::: "memory");
        __builtin_amdgcn_s_barrier();
    };
    // tail iteration (guarded, conservative drain)
    auto iter_tail = [&](int t, const char* Ac, char* An, const char* Bc, char* Bn3,
                         const f32x4* sStore, f32x4* sFill) {
        if (t + 3 < NKT) issueB(t + 3, Bn3);
        bf16x8 bfr[4];
        readB(Bc, bfr);
        compute_h(Ac, 0, bfr);
        if (t + 1 < NKT) storeA(sStore, An);
        if (t + 4 < NKT) issueA(t + 4, sFill);
        compute_h(Ac, 1, bfr);
        if (t + 1 < NKT) {
            asm volatile("s_waitcnt vmcnt(0) lgkmcnt(0)" ::: "memory");
            __builtin_amdgcn_s_barrier();
        }
    };

    // ---- prologue: A(0)->LDS; A(1..3) + B(1..2) in flight; B(0) landed -----
    issueA(0, s0);
    issueB(0, Bq0);
    storeA(s0, Ab0);                 // auto-waits A(0) loads
    issueA(1, s1);
    asm volatile("s_waitcnt vmcnt(0)" ::: "memory");   // one-time full drain (B(0)+A(1))
    issueB(1, Bq1);
    issueA(2, s2);
    issueB(2, Bq2);
    issueA(3, s3);
    asm volatile("s_waitcnt lgkmcnt(0)" ::: "memory");
    __builtin_amdgcn_s_barrier();

    // main: t = 0..23, unrolled by 4 (all buffer/set indices compile-time)
    for (int t = 0; t < 24; t += 4) {
        iter_main(t,     Ab0, Ab1, Bq0, Bq3, s1, s0);
        iter_main(t + 1, Ab1, Ab0, Bq1, Bq0, s2, s1);
        iter_main(t + 2, Ab0, Ab1, Bq2, Bq1, s3, s2);
        iter_main(t + 3, Ab1, Ab0, Bq3, Bq2, s0, s3);
    }
    // tail: t = 24..31
    iter_tail(24, Ab0, Ab1, Bq0, Bq3, s1, s0);
    iter_tail(25, Ab1, Ab0, Bq1, Bq0, s2, s1);
    iter_tail(26, Ab0, Ab1, Bq2, Bq1, s3, s2);
    iter_tail(27, Ab1, Ab0, Bq3, Bq2, s0, s3);
    iter_tail(28, Ab0, Ab1, Bq0, Bq3, s1, s0);
    iter_tail(29, Ab1, Ab0, Bq1, Bq0, s2, s1);
    iter_tail(30, Ab0, Ab1, Bq2, Bq1, s3, s2);
    iter_tail(31, Ab1, Ab0, Bq3, Bq2, s0, s3);
    __syncthreads();                 // LDS free for epilogue reuse

    // ---- epilogue: per-wave LDS transpose -> full-line f32x4 stores --------
    float* tb = (float*)smem + wn * 1280;
    const int nbase = bn * BN + wn * 64;
    float bv[4];
#pragma unroll
    for (int nf = 0; nf < 4; ++nf) bv[nf] = bias[nbase + nf * 16 + (lane & 15)];

#pragma unroll
    for (int mf = 0; mf < 8; ++mf) {
#pragma unroll
        for (int nf = 0; nf < 4; ++nf)
#pragma unroll
            for (int j = 0; j < 4; ++j) {
                const int r = (lane >> 4) * 4 + j;
                const int c = nf * 16 + (lane & 15);
                tb[r * 80 + c] = acc[mf][nf][j] + bv[nf];
            }
        __syncthreads();
#pragma unroll
        for (int jj = 0; jj < 4; ++jj) {
            const int rr = jj * 4 + (lane >> 4);
            const int cc = (lane & 15) * 4;
            f32x4 v = *(const f32x4*)&tb[rr * 80 + cc];
            *(f32x4*)&Out[(size_t)(m0 + mf * 16 + rr) * DN + nbase + cc] = v;
        }
        __syncthreads();
    }
}

extern "C" void kernel_launch(void* const* d_in, const int* in_sizes, int n_in,
                              void* d_out, int out_size, void* d_ws, size_t ws_size,
                              hipStream_t stream) {
    const float* x  = (const float*)d_in[0];
    const float* W  = (const float*)d_in[1];
    const float* b  = (const float*)d_in[2];
    const float* Vr = (const float*)d_in[3];
    const float* C  = (const float*)d_in[4];
    float* out = (float*)d_out;

    const int M = in_sizes[0] / DK;            // 65536
    bf16_t* WeffSw = (bf16_t*)d_ws;            // 2 MB pre-swizzled W_eff

    weff_kernel<<<DN, 128, 0, stream>>>(W, Vr, C, WeffSw);

    const int mtiles = M / BM;                 // 512
    const int nwg = mtiles * (DN / BN);        // 1024
    corrlin_gemm_kernel<<<nwg, 512, 0, stream>>>(x, WeffSw, b, out);
}